// Round 1
// baseline (579.163 us; speedup 1.0000x reference)
//
#include <hip/hip_runtime.h>
#include <math.h>

#define NEG_SLOPE 0.2f

// ---------------------------------------------------------------------------
// AtomEncoder: x[n,d] = sum_j emb[feat[n,j] + offset[j]][d]
// One wave (64 lanes = 64 dims) per node, 4 nodes per 256-thread block.
// ---------------------------------------------------------------------------
__global__ __launch_bounds__(256) void embed_kernel(
        const int* __restrict__ feat, const float* __restrict__ emb,
        float* __restrict__ x, int N) {
    const int offs[9] = {0, 119, 124, 136, 148, 158, 164, 170, 172};
    int sub  = threadIdx.x >> 6;
    int lane = threadIdx.x & 63;
    int n = blockIdx.x * 4 + sub;
    if (n >= N) return;
    float s = 0.f;
#pragma unroll
    for (int j = 0; j < 9; ++j) {
        int idx = feat[n * 9 + j] + offs[j];
        s += emb[idx * 64 + lane];
    }
    x[(size_t)n * 64 + lane] = s;
}

// ---------------------------------------------------------------------------
// Dual GEMM: xl = x @ Wl + bl ; xr = x @ Wr + br.  x:[N,64], W:[64,256].
// blockIdx.y in 0..3 selects (matrix, 128-col half). Tile: 64 rows x 128 cols,
// 256 threads, 8x4 register block per thread. K = 64 (single pass).
// ---------------------------------------------------------------------------
__global__ __launch_bounds__(256) void gemm_kernel(
        const float* __restrict__ x,
        const float* __restrict__ Wl, const float* __restrict__ Wr,
        const float* __restrict__ bl, const float* __restrict__ br,
        float* __restrict__ xl, float* __restrict__ xr, int N) {
    __shared__ float As[64][64];                 // [k][m]
    __shared__ __align__(16) float Bs[64][128];  // [k][c]
    int t  = threadIdx.x;
    int m0 = blockIdx.x * 64;
    int ct = blockIdx.y;  // 0,1 -> Wl ; 2,3 -> Wr
    const float* B    = (ct < 2) ? Wl : Wr;
    const float* bias = (ct < 2) ? bl : br;
    float*       out  = (ct < 2) ? xl : xr;
    int cb = (ct & 1) * 128;

    // Load A tile (transpose into [k][m]); stride-64 scalar writes -> 2-way (free)
    {
        int m   = t & 63;
        int kq0 = t >> 6;  // 0..3
        int row = m0 + m;
#pragma unroll
        for (int j = 0; j < 4; ++j) {
            int kq = kq0 + j * 4;  // 0..15
            float4 a = make_float4(0.f, 0.f, 0.f, 0.f);
            if (row < N) a = *(const float4*)(x + (size_t)row * 64 + kq * 4);
            As[kq * 4 + 0][m] = a.x;
            As[kq * 4 + 1][m] = a.y;
            As[kq * 4 + 2][m] = a.z;
            As[kq * 4 + 3][m] = a.w;
        }
    }
    // Load B tile
    {
        int c4 = t & 31;
        int k0 = t >> 5;  // 0..7
#pragma unroll
        for (int j = 0; j < 8; ++j) {
            int k = k0 + j * 8;
            *(float4*)(&Bs[k][c4 * 4]) = *(const float4*)(B + (size_t)k * 256 + cb + c4 * 4);
        }
    }
    __syncthreads();

    int tx = t & 31;  // col quad
    int ty = t >> 5;  // 0..7, rows ty + 8i
    float4 acc[8];
#pragma unroll
    for (int i = 0; i < 8; ++i) acc[i] = make_float4(0.f, 0.f, 0.f, 0.f);

#pragma unroll 8
    for (int k = 0; k < 64; ++k) {
        float4 b = *(const float4*)(&Bs[k][tx * 4]);
#pragma unroll
        for (int i = 0; i < 8; ++i) {
            float a = As[k][ty + i * 8];
            acc[i].x += a * b.x; acc[i].y += a * b.y;
            acc[i].z += a * b.z; acc[i].w += a * b.w;
        }
    }

    float4 bv = *(const float4*)(bias + cb + tx * 4);
#pragma unroll
    for (int i = 0; i < 8; ++i) {
        int row = m0 + ty + i * 8;
        if (row < N) {
            float4 o = acc[i];
            o.x += bv.x; o.y += bv.y; o.z += bv.z; o.w += bv.w;
            *(float4*)(out + (size_t)row * 256 + cb + tx * 4) = o;
        }
    }
}

// ---------------------------------------------------------------------------
// CSR build (dst-sorted incoming edge lists)
// ---------------------------------------------------------------------------
__global__ void hist_kernel(const int* __restrict__ dst, int* __restrict__ counts, int E) {
    int e = blockIdx.x * 256 + threadIdx.x;
    if (e < E) atomicAdd(&counts[dst[e]], 1);
}

// Block-level exclusive scan: 1024 elems / block (4 per thread)
__global__ void scan_block_kernel(const int* __restrict__ counts, int* __restrict__ excl,
                                  int* __restrict__ blockSums, int N) {
    __shared__ int lds[256];
    int b = blockIdx.x, t = threadIdx.x;
    int base = b * 1024 + t * 4;
    int v0 = (base + 0 < N) ? counts[base + 0] : 0;
    int v1 = (base + 1 < N) ? counts[base + 1] : 0;
    int v2 = (base + 2 < N) ? counts[base + 2] : 0;
    int v3 = (base + 3 < N) ? counts[base + 3] : 0;
    int s = v0 + v1 + v2 + v3;
    lds[t] = s;
    __syncthreads();
    for (int off = 1; off < 256; off <<= 1) {
        int add = (t >= off) ? lds[t - off] : 0;
        __syncthreads();
        lds[t] += add;
        __syncthreads();
    }
    int run = lds[t] - s;  // exclusive prefix for this thread
    if (base + 0 < N) excl[base + 0] = run; run += v0;
    if (base + 1 < N) excl[base + 1] = run; run += v1;
    if (base + 2 < N) excl[base + 2] = run; run += v2;
    if (base + 3 < N) excl[base + 3] = run;
    if (t == 255) blockSums[b] = lds[255];
}

__global__ void scan_sums_kernel(int* __restrict__ blockSums, int nb) {
    __shared__ int lds[64];
    int t = threadIdx.x;  // 64 threads; nb <= 64 required (N <= 65536)
    int v = (t < nb) ? blockSums[t] : 0;
    lds[t] = v;
    __syncthreads();
    for (int off = 1; off < 64; off <<= 1) {
        int add = (t >= off) ? lds[t - off] : 0;
        __syncthreads();
        lds[t] += add;
        __syncthreads();
    }
    if (t < nb) blockSums[t] = lds[t] - v;
}

__global__ void finalize_kernel(int* __restrict__ csr_off, const int* __restrict__ blockSums,
                                int* __restrict__ cursor, int N, int E) {
    int i = blockIdx.x * 256 + threadIdx.x;
    if (i < N) {
        int v = csr_off[i] + blockSums[i >> 10];
        csr_off[i] = v;
        cursor[i]  = v;
    }
    if (i == 0) csr_off[N] = E;
}

__global__ void scatter_kernel(const int* __restrict__ src, const int* __restrict__ dst,
                               int* __restrict__ cursor, int* __restrict__ csr_src, int E) {
    int e = blockIdx.x * 256 + threadIdx.x;
    if (e < E) {
        int pos = atomicAdd(&cursor[dst[e]], 1);
        csr_src[pos] = src[e];
    }
}

// ---------------------------------------------------------------------------
// GATv2 aggregation: one wave per destination node. Lane j owns feature quad
// 4j..4j+3 (head = j>>4). Single pass over incoming edges (+ self loop):
// logit via 16-lane butterfly reduce, unnormalized softmax accumulation,
// normalize + head-mean + bias (+ GELU) in epilogue. Writes x in place.
// ---------------------------------------------------------------------------
__global__ __launch_bounds__(256) void agg_kernel(
        const float* __restrict__ xl, const float* __restrict__ xr,
        const int* __restrict__ csr_off, const int* __restrict__ csr_src,
        const float* __restrict__ att,   // [4*64] this layer
        const float* __restrict__ gbias, // [64] this layer
        float* __restrict__ xout, int N, int apply_gelu) {
    int wave = threadIdx.x >> 6;
    int lane = threadIdx.x & 63;
    int n = blockIdx.x * 4 + wave;
    if (n >= N) return;

    float4 att4 = ((const float4*)att)[lane];
    float4 xr4  = *(const float4*)(xr + (size_t)n * 256 + lane * 4);
    float4 acc  = make_float4(0.f, 0.f, 0.f, 0.f);
    float denom = 0.f;

    int beg = csr_off[n], end = csr_off[n + 1];
    for (int k = beg; k <= end; ++k) {  // one extra iteration = self loop
        int s = (k < end) ? csr_src[k] : n;
        float4 xv = *(const float4*)(xl + (size_t)s * 256 + lane * 4);
        float m0 = xv.x + xr4.x; m0 = m0 > 0.f ? m0 : NEG_SLOPE * m0;
        float m1 = xv.y + xr4.y; m1 = m1 > 0.f ? m1 : NEG_SLOPE * m1;
        float m2 = xv.z + xr4.z; m2 = m2 > 0.f ? m2 : NEG_SLOPE * m2;
        float m3 = xv.w + xr4.w; m3 = m3 > 0.f ? m3 : NEG_SLOPE * m3;
        float p = m0 * att4.x + m1 * att4.y + m2 * att4.z + m3 * att4.w;
        p += __shfl_xor(p, 1);
        p += __shfl_xor(p, 2);
        p += __shfl_xor(p, 4);
        p += __shfl_xor(p, 8);   // full head-sum on all 16 lanes of the head
        float w = expf(p);       // no max-shift: logits are O(1), ratio identical
        denom += w;
        acc.x += w * xv.x; acc.y += w * xv.y;
        acc.z += w * xv.z; acc.w += w * xv.w;
    }

    float inv = 1.f / denom;  // per-head denom (redundant across the 16 lanes)
    float rx = acc.x * inv, ry = acc.y * inv, rz = acc.z * inv, rw = acc.w * inv;
    // head mean: fold heads together (lanes j, j^16, j^32, j^48 share d)
    rx += __shfl_xor(rx, 16); rx += __shfl_xor(rx, 32);
    ry += __shfl_xor(ry, 16); ry += __shfl_xor(ry, 32);
    rz += __shfl_xor(rz, 16); rz += __shfl_xor(rz, 32);
    rw += __shfl_xor(rw, 16); rw += __shfl_xor(rw, 32);

    if (lane < 16) {
        int d0 = lane * 4;
        float4 bv = *(const float4*)(gbias + d0);
        float ox = 0.25f * rx + bv.x;
        float oy = 0.25f * ry + bv.y;
        float oz = 0.25f * rz + bv.z;
        float ow = 0.25f * rw + bv.w;
        if (apply_gelu) {
            const float k = 0.70710678118654752440f;
            ox = 0.5f * ox * (1.f + erff(ox * k));
            oy = 0.5f * oy * (1.f + erff(oy * k));
            oz = 0.5f * oz * (1.f + erff(oz * k));
            ow = 0.5f * ow * (1.f + erff(ow * k));
        }
        *(float4*)(xout + (size_t)n * 64 + d0) = make_float4(ox, oy, oz, ow);
    }
}

// ---------------------------------------------------------------------------
// Global mean pool (batch is sorted) + classifier. Block per graph, 64 threads.
// Deterministic sequential sums; binary search for node range.
// ---------------------------------------------------------------------------
__global__ __launch_bounds__(64) void pool_kernel(
        const float* __restrict__ x, const int* __restrict__ batch,
        const float* __restrict__ Wc, const float* __restrict__ bc,
        float* __restrict__ out, int N, int G) {
    __shared__ float pooled[64];
    int g = blockIdx.x, t = threadIdx.x;
    int lo = 0, hi = N;
    while (lo < hi) { int mid = (lo + hi) >> 1; if (batch[mid] < g) lo = mid + 1; else hi = mid; }
    int beg = lo;
    hi = N;
    while (lo < hi) { int mid = (lo + hi) >> 1; if (batch[mid] < g + 1) lo = mid + 1; else hi = mid; }
    int end = lo;

    float acc = 0.f;
    for (int n = beg; n < end; ++n) acc += x[(size_t)n * 64 + t];
    int cnt = end - beg;
    pooled[t] = (cnt > 0) ? acc / (float)cnt : 0.f;  // max(cnt,1): empty -> 0
    __syncthreads();
    if (t < 10) {
        float o = bc[t];
        for (int d = 0; d < 64; ++d) o += pooled[d] * Wc[d * 10 + t];
        out[(size_t)g * 10 + t] = o;
    }
}

// ---------------------------------------------------------------------------
extern "C" void kernel_launch(void* const* d_in, const int* in_sizes, int n_in,
                              void* d_out, int out_size, void* d_ws, size_t ws_size,
                              hipStream_t stream) {
    const int*   feat  = (const int*)d_in[0];
    const int*   edges = (const int*)d_in[1];
    const int*   batch = (const int*)d_in[2];
    const float* emb   = (const float*)d_in[3];
    const float* Wl    = (const float*)d_in[4];
    const float* bl    = (const float*)d_in[5];
    const float* Wr    = (const float*)d_in[6];
    const float* br    = (const float*)d_in[7];
    const float* att   = (const float*)d_in[8];
    const float* gb    = (const float*)d_in[9];
    const float* Wc    = (const float*)d_in[10];
    const float* bc    = (const float*)d_in[11];
    float* out = (float*)d_out;

    const int N = in_sizes[2];
    const int E = in_sizes[1] / 2;
    const int G = out_size / 10;

    char* ws = (char*)d_ws;
    size_t off = 0;
    auto alloc = [&](size_t bytes) -> char* {
        char* p = ws + off;
        off = (off + bytes + 255) & ~(size_t)255;
        return p;
    };
    float* x         = (float*)alloc((size_t)N * 64 * 4);
    float* xl        = (float*)alloc((size_t)N * 256 * 4);
    float* xr        = (float*)alloc((size_t)N * 256 * 4);
    int*   counts    = (int*)alloc((size_t)N * 4);
    int*   csr_off   = (int*)alloc((size_t)(N + 1) * 4);
    int*   cursor    = (int*)alloc((size_t)N * 4);
    int*   csr_src   = (int*)alloc((size_t)E * 4);
    int*   blockSums = (int*)alloc(256 * 4);

    const int* srcv = edges;
    const int* dstv = edges + E;

    // 1) atom embedding
    hipLaunchKernelGGL(embed_kernel, dim3((N + 3) / 4), dim3(256), 0, stream, feat, emb, x, N);

    // 2) CSR by destination (self-loops handled inline in agg)
    hipMemsetAsync(counts, 0, (size_t)N * 4, stream);
    hipLaunchKernelGGL(hist_kernel, dim3((E + 255) / 256), dim3(256), 0, stream, dstv, counts, E);
    int nb = (N + 1023) / 1024;
    hipLaunchKernelGGL(scan_block_kernel, dim3(nb), dim3(256), 0, stream, counts, csr_off, blockSums, N);
    hipLaunchKernelGGL(scan_sums_kernel, dim3(1), dim3(64), 0, stream, blockSums, nb);
    hipLaunchKernelGGL(finalize_kernel, dim3((N + 255) / 256), dim3(256), 0, stream, csr_off, blockSums, cursor, N, E);
    hipLaunchKernelGGL(scatter_kernel, dim3((E + 255) / 256), dim3(256), 0, stream, srcv, dstv, cursor, csr_src, E);

    // 3) GATv2 layers
    for (int l = 0; l < 3; ++l) {
        hipLaunchKernelGGL(gemm_kernel, dim3((N + 63) / 64, 4), dim3(256), 0, stream,
                           x, Wl + (size_t)l * 64 * 256, Wr + (size_t)l * 64 * 256,
                           bl + l * 256, br + l * 256, xl, xr, N);
        hipLaunchKernelGGL(agg_kernel, dim3((N + 3) / 4), dim3(256), 0, stream,
                           xl, xr, csr_off, csr_src, att + l * 256, gb + l * 64,
                           x, N, (l < 2) ? 1 : 0);
    }

    // 4) pool + classify
    hipLaunchKernelGGL(pool_kernel, dim3(G), dim3(64), 0, stream, x, batch, Wc, bc, out, N, G);
}

// Round 2
// 543.057 us; speedup vs baseline: 1.0665x; 1.0665x over previous
//
#include <hip/hip_runtime.h>
#include <math.h>

#define NEG_SLOPE 0.2f

// ---------------------------------------------------------------------------
// AtomEncoder: x[n,d] = sum_j emb[feat[n,j] + offset[j]][d]
// One wave (64 lanes = 64 dims) per node, 4 nodes per 256-thread block.
// Also zeroes counts[n] (folds the memset dispatch away).
// ---------------------------------------------------------------------------
__global__ __launch_bounds__(256) void embed_kernel(
        const int* __restrict__ feat, const float* __restrict__ emb,
        float* __restrict__ x, int* __restrict__ counts, int N) {
    const int offs[9] = {0, 119, 124, 136, 148, 158, 164, 170, 172};
    int sub  = threadIdx.x >> 6;
    int lane = threadIdx.x & 63;
    int n = blockIdx.x * 4 + sub;
    if (n >= N) return;
    if (lane == 0) counts[n] = 0;
    float s = 0.f;
#pragma unroll
    for (int j = 0; j < 9; ++j) {
        int idx = feat[n * 9 + j] + offs[j];
        s += emb[idx * 64 + lane];
    }
    x[(size_t)n * 64 + lane] = s;
}

// ---------------------------------------------------------------------------
// Dual GEMM: xl = x @ Wl + bl ; xr = x @ Wr + br.  x:[N,64], W:[64,256].
// blockIdx.y in 0..3 selects (matrix, 128-col half). Tile: 64 rows x 128 cols,
// 256 threads. Register block: 8 CONTIGUOUS rows x 4 cols per thread so the
// A-tile LDS reads are two ds_read_b128 instead of 8 scalar ds_read_b32.
// ---------------------------------------------------------------------------
__global__ __launch_bounds__(256) void gemm_kernel(
        const float* __restrict__ x,
        const float* __restrict__ Wl, const float* __restrict__ Wr,
        const float* __restrict__ bl, const float* __restrict__ br,
        float* __restrict__ xl, float* __restrict__ xr, int N) {
    __shared__ __align__(16) float As[64][64];   // [k][m]
    __shared__ __align__(16) float Bs[64][128];  // [k][c]
    int t  = threadIdx.x;
    int m0 = blockIdx.x * 64;
    int ct = blockIdx.y;  // 0,1 -> Wl ; 2,3 -> Wr
    const float* B    = (ct < 2) ? Wl : Wr;
    const float* bias = (ct < 2) ? bl : br;
    float*       out  = (ct < 2) ? xl : xr;
    int cb = (ct & 1) * 128;

    // Load A tile (transpose into [k][m]); stride-64 scalar writes -> 2-way (free)
    {
        int m   = t & 63;
        int kq0 = t >> 6;  // 0..3
        int row = m0 + m;
#pragma unroll
        for (int j = 0; j < 4; ++j) {
            int kq = kq0 + j * 4;  // 0..15
            float4 a = make_float4(0.f, 0.f, 0.f, 0.f);
            if (row < N) a = *(const float4*)(x + (size_t)row * 64 + kq * 4);
            As[kq * 4 + 0][m] = a.x;
            As[kq * 4 + 1][m] = a.y;
            As[kq * 4 + 2][m] = a.z;
            As[kq * 4 + 3][m] = a.w;
        }
    }
    // Load B tile
    {
        int c4 = t & 31;
        int k0 = t >> 5;  // 0..7
#pragma unroll
        for (int j = 0; j < 8; ++j) {
            int k = k0 + j * 8;
            *(float4*)(&Bs[k][c4 * 4]) = *(const float4*)(B + (size_t)k * 256 + cb + c4 * 4);
        }
    }
    __syncthreads();

    int tx = t & 31;  // col quad: cols tx*4..+3
    int ty = t >> 5;  // row group: rows ty*8..+7 (contiguous!)
    float4 acc[8];
#pragma unroll
    for (int i = 0; i < 8; ++i) acc[i] = make_float4(0.f, 0.f, 0.f, 0.f);

#pragma unroll 8
    for (int k = 0; k < 64; ++k) {
        float4 b   = *(const float4*)(&Bs[k][tx * 4]);
        float4 alo = *(const float4*)(&As[k][ty * 8]);
        float4 ahi = *(const float4*)(&As[k][ty * 8 + 4]);
        acc[0].x += alo.x * b.x; acc[0].y += alo.x * b.y; acc[0].z += alo.x * b.z; acc[0].w += alo.x * b.w;
        acc[1].x += alo.y * b.x; acc[1].y += alo.y * b.y; acc[1].z += alo.y * b.z; acc[1].w += alo.y * b.w;
        acc[2].x += alo.z * b.x; acc[2].y += alo.z * b.y; acc[2].z += alo.z * b.z; acc[2].w += alo.z * b.w;
        acc[3].x += alo.w * b.x; acc[3].y += alo.w * b.y; acc[3].z += alo.w * b.z; acc[3].w += alo.w * b.w;
        acc[4].x += ahi.x * b.x; acc[4].y += ahi.x * b.y; acc[4].z += ahi.x * b.z; acc[4].w += ahi.x * b.w;
        acc[5].x += ahi.y * b.x; acc[5].y += ahi.y * b.y; acc[5].z += ahi.y * b.z; acc[5].w += ahi.y * b.w;
        acc[6].x += ahi.z * b.x; acc[6].y += ahi.z * b.y; acc[6].z += ahi.z * b.z; acc[6].w += ahi.z * b.w;
        acc[7].x += ahi.w * b.x; acc[7].y += ahi.w * b.y; acc[7].z += ahi.w * b.z; acc[7].w += ahi.w * b.w;
    }

    float4 bv = *(const float4*)(bias + cb + tx * 4);
#pragma unroll
    for (int i = 0; i < 8; ++i) {
        int row = m0 + ty * 8 + i;
        if (row < N) {
            float4 o = acc[i];
            o.x += bv.x; o.y += bv.y; o.z += bv.z; o.w += bv.w;
            *(float4*)(out + (size_t)row * 256 + cb + tx * 4) = o;
        }
    }
}

// ---------------------------------------------------------------------------
// CSR build (dst-sorted incoming edge lists)
// ---------------------------------------------------------------------------
__global__ void hist_kernel(const int* __restrict__ dst, int* __restrict__ counts, int E) {
    int e = blockIdx.x * 256 + threadIdx.x;
    if (e < E) atomicAdd(&counts[dst[e]], 1);
}

// Block-level exclusive scan: 1024 elems / block (4 per thread)
__global__ void scan_block_kernel(const int* __restrict__ counts, int* __restrict__ excl,
                                  int* __restrict__ blockSums, int N) {
    __shared__ int lds[256];
    int b = blockIdx.x, t = threadIdx.x;
    int base = b * 1024 + t * 4;
    int v0 = (base + 0 < N) ? counts[base + 0] : 0;
    int v1 = (base + 1 < N) ? counts[base + 1] : 0;
    int v2 = (base + 2 < N) ? counts[base + 2] : 0;
    int v3 = (base + 3 < N) ? counts[base + 3] : 0;
    int s = v0 + v1 + v2 + v3;
    lds[t] = s;
    __syncthreads();
    for (int off = 1; off < 256; off <<= 1) {
        int add = (t >= off) ? lds[t - off] : 0;
        __syncthreads();
        lds[t] += add;
        __syncthreads();
    }
    int run = lds[t] - s;  // exclusive prefix for this thread
    if (base + 0 < N) excl[base + 0] = run; run += v0;
    if (base + 1 < N) excl[base + 1] = run; run += v1;
    if (base + 2 < N) excl[base + 2] = run; run += v2;
    if (base + 3 < N) excl[base + 3] = run;
    if (t == 255) blockSums[b] = lds[255];
}

__global__ void scan_sums_kernel(int* __restrict__ blockSums, int nb) {
    __shared__ int lds[64];
    int t = threadIdx.x;  // 64 threads; nb <= 64 required (N <= 65536)
    int v = (t < nb) ? blockSums[t] : 0;
    lds[t] = v;
    __syncthreads();
    for (int off = 1; off < 64; off <<= 1) {
        int add = (t >= off) ? lds[t - off] : 0;
        __syncthreads();
        lds[t] += add;
        __syncthreads();
    }
    if (t < nb) blockSums[t] = lds[t] - v;
}

__global__ void finalize_kernel(int* __restrict__ csr_off, const int* __restrict__ blockSums,
                                int* __restrict__ cursor, int N, int E) {
    int i = blockIdx.x * 256 + threadIdx.x;
    if (i < N) {
        int v = csr_off[i] + blockSums[i >> 10];
        csr_off[i] = v;
        cursor[i]  = v;
    }
    if (i == 0) csr_off[N] = E;
}

__global__ void scatter_kernel(const int* __restrict__ src, const int* __restrict__ dst,
                               int* __restrict__ cursor, int* __restrict__ csr_src, int E) {
    int e = blockIdx.x * 256 + threadIdx.x;
    if (e < E) {
        int pos = atomicAdd(&cursor[dst[e]], 1);
        csr_src[pos] = src[e];
    }
}

// ---------------------------------------------------------------------------
// GATv2 aggregation: one wave per destination node. Lane j owns feature quad
// 4j..4j+3 (head = j>>4). 4-deep software-pipelined gather: issue 4 csr_src
// reads + 4 independent 1KB row gathers before any compute so each wave keeps
// ~4 outstanding HBM gathers (latency-bound -> BW-bound). Tail groups are
// predicated wave-uniformly (rem is per-node). Self loop = virtual edge endv.
// ---------------------------------------------------------------------------
__global__ __launch_bounds__(256) void agg_kernel(
        const float* __restrict__ xl, const float* __restrict__ xr,
        const int* __restrict__ csr_off, const int* __restrict__ csr_src,
        const float* __restrict__ att,   // [4*64] this layer
        const float* __restrict__ gbias, // [64] this layer
        float* __restrict__ xout, int N, int apply_gelu) {
    int wave = threadIdx.x >> 6;
    int lane = threadIdx.x & 63;
    int n = blockIdx.x * 4 + wave;
    if (n >= N) return;

    float4 att4 = ((const float4*)att)[lane];
    float4 xr4  = *(const float4*)(xr + (size_t)n * 256 + lane * 4);
    float4 acc  = make_float4(0.f, 0.f, 0.f, 0.f);
    float denom = 0.f;

    int beg  = csr_off[n];
    int endv = csr_off[n + 1];
    int m = endv - beg + 1;  // incoming edges + self loop

    for (int base = 0; base < m; base += 4) {
        int rem = m - base;          // wave-uniform
        int kk = beg + base;
        // stage 1: indices (contiguous csr_src reads; invalid slots reuse s0)
        int s0 = (kk < endv) ? csr_src[kk] : n;
        int s1 = (rem > 1) ? ((kk + 1 < endv) ? csr_src[kk + 1] : n) : s0;
        int s2 = (rem > 2) ? ((kk + 2 < endv) ? csr_src[kk + 2] : n) : s0;
        int s3 = (rem > 3) ? ((kk + 3 < endv) ? csr_src[kk + 3] : n) : s0;
        // stage 2: issue all gathers (independent -> 4 outstanding per wave)
        float4 v0 = *(const float4*)(xl + (size_t)s0 * 256 + lane * 4);
        float4 v1 = *(const float4*)(xl + (size_t)s1 * 256 + lane * 4);
        float4 v2 = *(const float4*)(xl + (size_t)s2 * 256 + lane * 4);
        float4 v3 = *(const float4*)(xl + (size_t)s3 * 256 + lane * 4);
        // stage 3: process (guards are wave-uniform -> no divergence)
#pragma unroll
        for (int j = 0; j < 4; ++j) {
            if (j >= rem) break;
            float4 xv = (j == 0) ? v0 : (j == 1) ? v1 : (j == 2) ? v2 : v3;
            float t0 = xv.x + xr4.x; t0 = t0 > 0.f ? t0 : NEG_SLOPE * t0;
            float t1 = xv.y + xr4.y; t1 = t1 > 0.f ? t1 : NEG_SLOPE * t1;
            float t2 = xv.z + xr4.z; t2 = t2 > 0.f ? t2 : NEG_SLOPE * t2;
            float t3 = xv.w + xr4.w; t3 = t3 > 0.f ? t3 : NEG_SLOPE * t3;
            float p = t0 * att4.x + t1 * att4.y + t2 * att4.z + t3 * att4.w;
            p += __shfl_xor(p, 1);
            p += __shfl_xor(p, 2);
            p += __shfl_xor(p, 4);
            p += __shfl_xor(p, 8);   // full head-sum on all 16 lanes of the head
            float w = __expf(p);     // no max-shift: logits O(1), ratio identical
            denom += w;
            acc.x += w * xv.x; acc.y += w * xv.y;
            acc.z += w * xv.z; acc.w += w * xv.w;
        }
    }

    float inv = 1.f / denom;  // per-head denom (redundant across the 16 lanes)
    float rx = acc.x * inv, ry = acc.y * inv, rz = acc.z * inv, rw = acc.w * inv;
    // head mean: fold heads together (lanes j, j^16, j^32, j^48 share d)
    rx += __shfl_xor(rx, 16); rx += __shfl_xor(rx, 32);
    ry += __shfl_xor(ry, 16); ry += __shfl_xor(ry, 32);
    rz += __shfl_xor(rz, 16); rz += __shfl_xor(rz, 32);
    rw += __shfl_xor(rw, 16); rw += __shfl_xor(rw, 32);

    if (lane < 16) {
        int d0 = lane * 4;
        float4 bv = *(const float4*)(gbias + d0);
        float ox = 0.25f * rx + bv.x;
        float oy = 0.25f * ry + bv.y;
        float oz = 0.25f * rz + bv.z;
        float ow = 0.25f * rw + bv.w;
        if (apply_gelu) {
            const float k = 0.70710678118654752440f;
            ox = 0.5f * ox * (1.f + erff(ox * k));
            oy = 0.5f * oy * (1.f + erff(oy * k));
            oz = 0.5f * oz * (1.f + erff(oz * k));
            ow = 0.5f * ow * (1.f + erff(ow * k));
        }
        *(float4*)(xout + (size_t)n * 64 + d0) = make_float4(ox, oy, oz, ow);
    }
}

// ---------------------------------------------------------------------------
// Global mean pool (batch is sorted) + classifier. Block per graph, 64 threads.
// Deterministic sequential sums; binary search for node range.
// ---------------------------------------------------------------------------
__global__ __launch_bounds__(64) void pool_kernel(
        const float* __restrict__ x, const int* __restrict__ batch,
        const float* __restrict__ Wc, const float* __restrict__ bc,
        float* __restrict__ out, int N, int G) {
    __shared__ float pooled[64];
    int g = blockIdx.x, t = threadIdx.x;
    int lo = 0, hi = N;
    while (lo < hi) { int mid = (lo + hi) >> 1; if (batch[mid] < g) lo = mid + 1; else hi = mid; }
    int beg = lo;
    hi = N;
    while (lo < hi) { int mid = (lo + hi) >> 1; if (batch[mid] < g + 1) lo = mid + 1; else hi = mid; }
    int end = lo;

    float acc = 0.f;
    for (int n = beg; n < end; ++n) acc += x[(size_t)n * 64 + t];
    int cnt = end - beg;
    pooled[t] = (cnt > 0) ? acc / (float)cnt : 0.f;  // max(cnt,1): empty -> 0
    __syncthreads();
    if (t < 10) {
        float o = bc[t];
        for (int d = 0; d < 64; ++d) o += pooled[d] * Wc[d * 10 + t];
        out[(size_t)g * 10 + t] = o;
    }
}

// ---------------------------------------------------------------------------
extern "C" void kernel_launch(void* const* d_in, const int* in_sizes, int n_in,
                              void* d_out, int out_size, void* d_ws, size_t ws_size,
                              hipStream_t stream) {
    const int*   feat  = (const int*)d_in[0];
    const int*   edges = (const int*)d_in[1];
    const int*   batch = (const int*)d_in[2];
    const float* emb   = (const float*)d_in[3];
    const float* Wl    = (const float*)d_in[4];
    const float* bl    = (const float*)d_in[5];
    const float* Wr    = (const float*)d_in[6];
    const float* br    = (const float*)d_in[7];
    const float* att   = (const float*)d_in[8];
    const float* gb    = (const float*)d_in[9];
    const float* Wc    = (const float*)d_in[10];
    const float* bc    = (const float*)d_in[11];
    float* out = (float*)d_out;

    const int N = in_sizes[2];
    const int E = in_sizes[1] / 2;
    const int G = out_size / 10;

    char* ws = (char*)d_ws;
    size_t off = 0;
    auto alloc = [&](size_t bytes) -> char* {
        char* p = ws + off;
        off = (off + bytes + 255) & ~(size_t)255;
        return p;
    };
    float* x         = (float*)alloc((size_t)N * 64 * 4);
    float* xl        = (float*)alloc((size_t)N * 256 * 4);
    float* xr        = (float*)alloc((size_t)N * 256 * 4);
    int*   counts    = (int*)alloc((size_t)N * 4);
    int*   csr_off   = (int*)alloc((size_t)(N + 1) * 4);
    int*   cursor    = (int*)alloc((size_t)N * 4);
    int*   csr_src   = (int*)alloc((size_t)E * 4);
    int*   blockSums = (int*)alloc(256 * 4);

    const int* srcv = edges;
    const int* dstv = edges + E;

    // 1) atom embedding (+ counts zeroing)
    hipLaunchKernelGGL(embed_kernel, dim3((N + 3) / 4), dim3(256), 0, stream, feat, emb, x, counts, N);

    // 2) CSR by destination (self-loops handled inline in agg)
    hipLaunchKernelGGL(hist_kernel, dim3((E + 255) / 256), dim3(256), 0, stream, dstv, counts, E);
    int nb = (N + 1023) / 1024;
    hipLaunchKernelGGL(scan_block_kernel, dim3(nb), dim3(256), 0, stream, counts, csr_off, blockSums, N);
    hipLaunchKernelGGL(scan_sums_kernel, dim3(1), dim3(64), 0, stream, blockSums, nb);
    hipLaunchKernelGGL(finalize_kernel, dim3((N + 255) / 256), dim3(256), 0, stream, csr_off, blockSums, cursor, N, E);
    hipLaunchKernelGGL(scatter_kernel, dim3((E + 255) / 256), dim3(256), 0, stream, srcv, dstv, cursor, csr_src, E);

    // 3) GATv2 layers
    for (int l = 0; l < 3; ++l) {
        hipLaunchKernelGGL(gemm_kernel, dim3((N + 63) / 64, 4), dim3(256), 0, stream,
                           x, Wl + (size_t)l * 64 * 256, Wr + (size_t)l * 64 * 256,
                           bl + l * 256, br + l * 256, xl, xr, N);
        hipLaunchKernelGGL(agg_kernel, dim3((N + 3) / 4), dim3(256), 0, stream,
                           xl, xr, csr_off, csr_src, att + l * 256, gb + l * 64,
                           x, N, (l < 2) ? 1 : 0);
    }

    // 4) pool + classify
    hipLaunchKernelGGL(pool_kernel, dim3(G), dim3(64), 0, stream, x, batch, Wc, bc, out, N, G);
}

// Round 3
// 540.270 us; speedup vs baseline: 1.0720x; 1.0052x over previous
//
#include <hip/hip_runtime.h>
#include <math.h>

#define NEG_SLOPE 0.2f

// ---------------------------------------------------------------------------
// AtomEncoder: x[n,d] = sum_j emb[feat[n,j] + offset[j]][d]
// One wave (64 lanes = 64 dims) per node, 4 nodes per 256-thread block.
// Also inits counts[n] = 1 (self-loop lives in the CSR segment).
// ---------------------------------------------------------------------------
__global__ __launch_bounds__(256) void embed_kernel(
        const int* __restrict__ feat, const float* __restrict__ emb,
        float* __restrict__ x, int* __restrict__ counts, int N) {
    const int offs[9] = {0, 119, 124, 136, 148, 158, 164, 170, 172};
    int sub  = threadIdx.x >> 6;
    int lane = threadIdx.x & 63;
    int n = blockIdx.x * 4 + sub;
    if (n >= N) return;
    if (lane == 0) counts[n] = 1;  // self loop pre-counted
    float s = 0.f;
#pragma unroll
    for (int j = 0; j < 9; ++j) {
        int idx = feat[n * 9 + j] + offs[j];
        s += emb[idx * 64 + lane];
    }
    x[(size_t)n * 64 + lane] = s;
}

// ---------------------------------------------------------------------------
// Dual GEMM: xl = x @ Wl + bl ; xr = x @ Wr + br.  x:[N,64], W:[64,256].
// blockIdx.y in 0..3 selects (matrix, 128-col half). Tile: 64 rows x 128 cols,
// 256 threads. Register block: 8 contiguous rows x 4 cols per thread (A reads
// are two ds_read_b128).
// ---------------------------------------------------------------------------
__global__ __launch_bounds__(256) void gemm_kernel(
        const float* __restrict__ x,
        const float* __restrict__ Wl, const float* __restrict__ Wr,
        const float* __restrict__ bl, const float* __restrict__ br,
        float* __restrict__ xl, float* __restrict__ xr, int N) {
    __shared__ __align__(16) float As[64][64];   // [k][m]
    __shared__ __align__(16) float Bs[64][128];  // [k][c]
    int t  = threadIdx.x;
    int m0 = blockIdx.x * 64;
    int ct = blockIdx.y;  // 0,1 -> Wl ; 2,3 -> Wr
    const float* B    = (ct < 2) ? Wl : Wr;
    const float* bias = (ct < 2) ? bl : br;
    float*       out  = (ct < 2) ? xl : xr;
    int cb = (ct & 1) * 128;

    {
        int m   = t & 63;
        int kq0 = t >> 6;  // 0..3
        int row = m0 + m;
#pragma unroll
        for (int j = 0; j < 4; ++j) {
            int kq = kq0 + j * 4;  // 0..15
            float4 a = make_float4(0.f, 0.f, 0.f, 0.f);
            if (row < N) a = *(const float4*)(x + (size_t)row * 64 + kq * 4);
            As[kq * 4 + 0][m] = a.x;
            As[kq * 4 + 1][m] = a.y;
            As[kq * 4 + 2][m] = a.z;
            As[kq * 4 + 3][m] = a.w;
        }
    }
    {
        int c4 = t & 31;
        int k0 = t >> 5;  // 0..7
#pragma unroll
        for (int j = 0; j < 8; ++j) {
            int k = k0 + j * 8;
            *(float4*)(&Bs[k][c4 * 4]) = *(const float4*)(B + (size_t)k * 256 + cb + c4 * 4);
        }
    }
    __syncthreads();

    int tx = t & 31;  // col quad: cols tx*4..+3
    int ty = t >> 5;  // row group: rows ty*8..+7
    float4 acc[8];
#pragma unroll
    for (int i = 0; i < 8; ++i) acc[i] = make_float4(0.f, 0.f, 0.f, 0.f);

#pragma unroll 8
    for (int k = 0; k < 64; ++k) {
        float4 b   = *(const float4*)(&Bs[k][tx * 4]);
        float4 alo = *(const float4*)(&As[k][ty * 8]);
        float4 ahi = *(const float4*)(&As[k][ty * 8 + 4]);
        acc[0].x += alo.x * b.x; acc[0].y += alo.x * b.y; acc[0].z += alo.x * b.z; acc[0].w += alo.x * b.w;
        acc[1].x += alo.y * b.x; acc[1].y += alo.y * b.y; acc[1].z += alo.y * b.z; acc[1].w += alo.y * b.w;
        acc[2].x += alo.z * b.x; acc[2].y += alo.z * b.y; acc[2].z += alo.z * b.z; acc[2].w += alo.z * b.w;
        acc[3].x += alo.w * b.x; acc[3].y += alo.w * b.y; acc[3].z += alo.w * b.z; acc[3].w += alo.w * b.w;
        acc[4].x += ahi.x * b.x; acc[4].y += ahi.x * b.y; acc[4].z += ahi.x * b.z; acc[4].w += ahi.x * b.w;
        acc[5].x += ahi.y * b.x; acc[5].y += ahi.y * b.y; acc[5].z += ahi.y * b.z; acc[5].w += ahi.y * b.w;
        acc[6].x += ahi.z * b.x; acc[6].y += ahi.z * b.y; acc[6].z += ahi.z * b.z; acc[6].w += ahi.z * b.w;
        acc[7].x += ahi.w * b.x; acc[7].y += ahi.w * b.y; acc[7].z += ahi.w * b.z; acc[7].w += ahi.w * b.w;
    }

    float4 bv = *(const float4*)(bias + cb + tx * 4);
#pragma unroll
    for (int i = 0; i < 8; ++i) {
        int row = m0 + ty * 8 + i;
        if (row < N) {
            float4 o = acc[i];
            o.x += bv.x; o.y += bv.y; o.z += bv.z; o.w += bv.w;
            *(float4*)(out + (size_t)row * 256 + cb + tx * 4) = o;
        }
    }
}

// ---------------------------------------------------------------------------
// CSR build (dst-sorted incoming edge lists; slot 0 of each segment = self loop)
// ---------------------------------------------------------------------------
__global__ void hist_kernel(const int* __restrict__ dst, int* __restrict__ counts, int E) {
    int e = blockIdx.x * 256 + threadIdx.x;
    if (e < E) atomicAdd(&counts[dst[e]], 1);
}

__global__ void scan_block_kernel(const int* __restrict__ counts, int* __restrict__ excl,
                                  int* __restrict__ blockSums, int N) {
    __shared__ int lds[256];
    int b = blockIdx.x, t = threadIdx.x;
    int base = b * 1024 + t * 4;
    int v0 = (base + 0 < N) ? counts[base + 0] : 0;
    int v1 = (base + 1 < N) ? counts[base + 1] : 0;
    int v2 = (base + 2 < N) ? counts[base + 2] : 0;
    int v3 = (base + 3 < N) ? counts[base + 3] : 0;
    int s = v0 + v1 + v2 + v3;
    lds[t] = s;
    __syncthreads();
    for (int off = 1; off < 256; off <<= 1) {
        int add = (t >= off) ? lds[t - off] : 0;
        __syncthreads();
        lds[t] += add;
        __syncthreads();
    }
    int run = lds[t] - s;
    if (base + 0 < N) excl[base + 0] = run; run += v0;
    if (base + 1 < N) excl[base + 1] = run; run += v1;
    if (base + 2 < N) excl[base + 2] = run; run += v2;
    if (base + 3 < N) excl[base + 3] = run;
    if (t == 255) blockSums[b] = lds[255];
}

__global__ void scan_sums_kernel(int* __restrict__ blockSums, int nb) {
    __shared__ int lds[64];
    int t = threadIdx.x;  // nb <= 64 required (N <= 65536)
    int v = (t < nb) ? blockSums[t] : 0;
    lds[t] = v;
    __syncthreads();
    for (int off = 1; off < 64; off <<= 1) {
        int add = (t >= off) ? lds[t - off] : 0;
        __syncthreads();
        lds[t] += add;
        __syncthreads();
    }
    if (t < nb) blockSums[t] = lds[t] - v;
}

__global__ void finalize_kernel(int* __restrict__ csr_off, const int* __restrict__ blockSums,
                                int* __restrict__ cursor, int* __restrict__ csr_src,
                                int N, int total) {
    int i = blockIdx.x * 256 + threadIdx.x;
    if (i < N) {
        int v = csr_off[i] + blockSums[i >> 10];
        csr_off[i] = v;
        csr_src[v] = i;    // self loop at segment head
        cursor[i]  = v + 1;
    }
    if (i == 0) csr_off[N] = total;
}

__global__ void scatter_kernel(const int* __restrict__ src, const int* __restrict__ dst,
                               int* __restrict__ cursor, int* __restrict__ csr_src, int E) {
    int e = blockIdx.x * 256 + threadIdx.x;
    if (e < E) {
        int pos = atomicAdd(&cursor[dst[e]], 1);
        csr_src[pos] = src[e];
    }
}

// ---------------------------------------------------------------------------
// GATv2 aggregation: one wave per destination node. Lane j owns feature quad
// 4j..4j+3 (head = j>>4). Software pipeline: gathers for group g+1 are issued
// BEFORE computing group g; within a group the 4 edges' shfl reductions are
// batched per round (4 independent DS ops per round instead of a 16-deep
// dependent chain). CSR segments include the self loop; tail slots clamp to
// the last valid edge (valid data) and are excluded from accumulation by
// wave-uniform guards.
// ---------------------------------------------------------------------------
__global__ __launch_bounds__(256) void agg_kernel(
        const float* __restrict__ xl, const float* __restrict__ xr,
        const int* __restrict__ csr_off, const int* __restrict__ csr_src,
        const float* __restrict__ att,   // [4*64] this layer
        const float* __restrict__ gbias, // [64] this layer
        float* __restrict__ xout, int N, int apply_gelu) {
    int wave = threadIdx.x >> 6;
    int lane = threadIdx.x & 63;
    int n = blockIdx.x * 4 + wave;
    if (n >= N) return;

    float4 att4 = ((const float4*)att)[lane];
    float4 xr4  = *(const float4*)(xr + (size_t)n * 256 + lane * 4);
    float ax = 0.f, ay = 0.f, az = 0.f, aw = 0.f, denom = 0.f;

    int beg  = csr_off[n];
    int end  = csr_off[n + 1];   // includes self loop -> m >= 1
    int m    = end - beg;
    int last = end - 1;

    const float* xlp = xl + (size_t)lane * 4;

    auto logit = [&](const float4& v) -> float {
        float s0 = v.x + xr4.x, s1 = v.y + xr4.y, s2 = v.z + xr4.z, s3 = v.w + xr4.w;
        float t0 = fmaxf(s0, NEG_SLOPE * s0);  // lrelu(t) = max(t, 0.2t)
        float t1 = fmaxf(s1, NEG_SLOPE * s1);
        float t2 = fmaxf(s2, NEG_SLOPE * s2);
        float t3 = fmaxf(s3, NEG_SLOPE * s3);
        return t0 * att4.x + t1 * att4.y + t2 * att4.z + t3 * att4.w;
    };

    // prefetch group 0 (indices wave-uniform -> s_load; clamp keeps them valid)
    int i0 = csr_src[beg];
    int i1 = csr_src[min(beg + 1, last)];
    int i2 = csr_src[min(beg + 2, last)];
    int i3 = csr_src[min(beg + 3, last)];
    float4 a0 = *(const float4*)(xlp + (size_t)i0 * 256);
    float4 a1 = *(const float4*)(xlp + (size_t)i1 * 256);
    float4 a2 = *(const float4*)(xlp + (size_t)i2 * 256);
    float4 a3 = *(const float4*)(xlp + (size_t)i3 * 256);

    for (int base = 0; base < m; base += 4) {
        int rem = m - base;                 // wave-uniform
        bool more = (base + 4) < m;
        float4 b0, b1, b2, b3;
        if (more) {                         // issue next group's loads NOW
            int kn = beg + base + 4;
            int j0 = csr_src[kn];
            int j1 = csr_src[min(kn + 1, last)];
            int j2 = csr_src[min(kn + 2, last)];
            int j3 = csr_src[min(kn + 3, last)];
            b0 = *(const float4*)(xlp + (size_t)j0 * 256);
            b1 = *(const float4*)(xlp + (size_t)j1 * 256);
            b2 = *(const float4*)(xlp + (size_t)j2 * 256);
            b3 = *(const float4*)(xlp + (size_t)j3 * 256);
        }

        float p0 = logit(a0), p1 = logit(a1), p2 = logit(a2), p3 = logit(a3);
        // batched butterfly rounds: 4 independent DS ops per round
        p0 += __shfl_xor(p0, 1); p1 += __shfl_xor(p1, 1); p2 += __shfl_xor(p2, 1); p3 += __shfl_xor(p3, 1);
        p0 += __shfl_xor(p0, 2); p1 += __shfl_xor(p1, 2); p2 += __shfl_xor(p2, 2); p3 += __shfl_xor(p3, 2);
        p0 += __shfl_xor(p0, 4); p1 += __shfl_xor(p1, 4); p2 += __shfl_xor(p2, 4); p3 += __shfl_xor(p3, 4);
        p0 += __shfl_xor(p0, 8); p1 += __shfl_xor(p1, 8); p2 += __shfl_xor(p2, 8); p3 += __shfl_xor(p3, 8);
        float w0 = __expf(p0), w1 = __expf(p1), w2 = __expf(p2), w3 = __expf(p3);

        denom += w0; ax += w0 * a0.x; ay += w0 * a0.y; az += w0 * a0.z; aw += w0 * a0.w;
        if (rem > 1) { denom += w1; ax += w1 * a1.x; ay += w1 * a1.y; az += w1 * a1.z; aw += w1 * a1.w; }
        if (rem > 2) { denom += w2; ax += w2 * a2.x; ay += w2 * a2.y; az += w2 * a2.z; aw += w2 * a2.w; }
        if (rem > 3) { denom += w3; ax += w3 * a3.x; ay += w3 * a3.y; az += w3 * a3.z; aw += w3 * a3.w; }

        if (more) { a0 = b0; a1 = b1; a2 = b2; a3 = b3; }
    }

    float inv = 1.f / denom;  // per-head denom (redundant across the 16 lanes)
    float rx = ax * inv, ry = ay * inv, rz = az * inv, rw = aw * inv;
    // head mean: fold heads together (lanes j, j^16, j^32, j^48 share d)
    rx += __shfl_xor(rx, 16); rx += __shfl_xor(rx, 32);
    ry += __shfl_xor(ry, 16); ry += __shfl_xor(ry, 32);
    rz += __shfl_xor(rz, 16); rz += __shfl_xor(rz, 32);
    rw += __shfl_xor(rw, 16); rw += __shfl_xor(rw, 32);

    if (lane < 16) {
        int d0 = lane * 4;
        float4 bv = *(const float4*)(gbias + d0);
        float ox = 0.25f * rx + bv.x;
        float oy = 0.25f * ry + bv.y;
        float oz = 0.25f * rz + bv.z;
        float ow = 0.25f * rw + bv.w;
        if (apply_gelu) {
            const float kk = 0.70710678118654752440f;
            ox = 0.5f * ox * (1.f + erff(ox * kk));
            oy = 0.5f * oy * (1.f + erff(oy * kk));
            oz = 0.5f * oz * (1.f + erff(oz * kk));
            ow = 0.5f * ow * (1.f + erff(ow * kk));
        }
        *(float4*)(xout + (size_t)n * 64 + d0) = make_float4(ox, oy, oz, ow);
    }
}

// ---------------------------------------------------------------------------
// Global mean pool (batch is sorted) + classifier. Block per graph, 64 threads.
// ---------------------------------------------------------------------------
__global__ __launch_bounds__(64) void pool_kernel(
        const float* __restrict__ x, const int* __restrict__ batch,
        const float* __restrict__ Wc, const float* __restrict__ bc,
        float* __restrict__ out, int N, int G) {
    __shared__ float pooled[64];
    int g = blockIdx.x, t = threadIdx.x;
    int lo = 0, hi = N;
    while (lo < hi) { int mid = (lo + hi) >> 1; if (batch[mid] < g) lo = mid + 1; else hi = mid; }
    int beg = lo;
    hi = N;
    while (lo < hi) { int mid = (lo + hi) >> 1; if (batch[mid] < g + 1) lo = mid + 1; else hi = mid; }
    int end = lo;

    float acc = 0.f;
    for (int n = beg; n < end; ++n) acc += x[(size_t)n * 64 + t];
    int cnt = end - beg;
    pooled[t] = (cnt > 0) ? acc / (float)cnt : 0.f;
    __syncthreads();
    if (t < 10) {
        float o = bc[t];
        for (int d = 0; d < 64; ++d) o += pooled[d] * Wc[d * 10 + t];
        out[(size_t)g * 10 + t] = o;
    }
}

// ---------------------------------------------------------------------------
extern "C" void kernel_launch(void* const* d_in, const int* in_sizes, int n_in,
                              void* d_out, int out_size, void* d_ws, size_t ws_size,
                              hipStream_t stream) {
    const int*   feat  = (const int*)d_in[0];
    const int*   edges = (const int*)d_in[1];
    const int*   batch = (const int*)d_in[2];
    const float* emb   = (const float*)d_in[3];
    const float* Wl    = (const float*)d_in[4];
    const float* bl    = (const float*)d_in[5];
    const float* Wr    = (const float*)d_in[6];
    const float* br    = (const float*)d_in[7];
    const float* att   = (const float*)d_in[8];
    const float* gb    = (const float*)d_in[9];
    const float* Wc    = (const float*)d_in[10];
    const float* bc    = (const float*)d_in[11];
    float* out = (float*)d_out;

    const int N = in_sizes[2];
    const int E = in_sizes[1] / 2;
    const int G = out_size / 10;

    char* ws = (char*)d_ws;
    size_t off = 0;
    auto alloc = [&](size_t bytes) -> char* {
        char* p = ws + off;
        off = (off + bytes + 255) & ~(size_t)255;
        return p;
    };
    float* x         = (float*)alloc((size_t)N * 64 * 4);
    float* xl        = (float*)alloc((size_t)N * 256 * 4);
    float* xr        = (float*)alloc((size_t)N * 256 * 4);
    int*   counts    = (int*)alloc((size_t)N * 4);
    int*   csr_off   = (int*)alloc((size_t)(N + 1) * 4);
    int*   cursor    = (int*)alloc((size_t)N * 4);
    int*   csr_src   = (int*)alloc((size_t)(E + N) * 4);
    int*   blockSums = (int*)alloc(256 * 4);

    const int* srcv = edges;
    const int* dstv = edges + E;

    // 1) atom embedding (+ counts init to 1 for self loops)
    hipLaunchKernelGGL(embed_kernel, dim3((N + 3) / 4), dim3(256), 0, stream, feat, emb, x, counts, N);

    // 2) CSR by destination, self-loop at each segment head
    hipLaunchKernelGGL(hist_kernel, dim3((E + 255) / 256), dim3(256), 0, stream, dstv, counts, E);
    int nb = (N + 1023) / 1024;
    hipLaunchKernelGGL(scan_block_kernel, dim3(nb), dim3(256), 0, stream, counts, csr_off, blockSums, N);
    hipLaunchKernelGGL(scan_sums_kernel, dim3(1), dim3(64), 0, stream, blockSums, nb);
    hipLaunchKernelGGL(finalize_kernel, dim3((N + 255) / 256), dim3(256), 0, stream,
                       csr_off, blockSums, cursor, csr_src, N, E + N);
    hipLaunchKernelGGL(scatter_kernel, dim3((E + 255) / 256), dim3(256), 0, stream, srcv, dstv, cursor, csr_src, E);

    // 3) GATv2 layers
    for (int l = 0; l < 3; ++l) {
        hipLaunchKernelGGL(gemm_kernel, dim3((N + 63) / 64, 4), dim3(256), 0, stream,
                           x, Wl + (size_t)l * 64 * 256, Wr + (size_t)l * 64 * 256,
                           bl + l * 256, br + l * 256, xl, xr, N);
        hipLaunchKernelGGL(agg_kernel, dim3((N + 3) / 4), dim3(256), 0, stream,
                           xl, xr, csr_off, csr_src, att + l * 256, gb + l * 64,
                           x, N, (l < 2) ? 1 : 0);
    }

    // 4) pool + classify
    hipLaunchKernelGGL(pool_kernel, dim3(G), dim3(64), 0, stream, x, batch, Wc, bc, out, N, G);
}